// Round 2
// baseline (164.870 us; speedup 1.0000x reference)
//
#include <hip/hip_runtime.h>

// KLD RepPoints loss, R1: LDS-staged coalesced loads.
// R0 was latency-bound (VALUBusy 10%, HBM 11%): per-instruction loads had
// 64 lanes at stride 72B -> 64 cache lines per load instruction. Fix: block
// of 256 threads stages its 256-element slab (pred 18KB + target 8KB) into
// LDS with dense float4 loads (lane i <-> consecutive 16B), then each thread
// reads its own element from LDS (stride-18-dword = 4-way bank conflict,
// 1.58x on LDS throughput -- hidden behind the global stream).

__global__ __launch_bounds__(256) void kld_reppoints_kernel(
    const float* __restrict__ pred,    // [n][9][2]
    const float* __restrict__ target,  // [n][4][2]
    float* __restrict__ out,           // [1]
    int n_total, float inv_n)
{
    __shared__ float sp[256 * 18];     // 18432 B
    __shared__ float st[256 * 8];      //  8192 B

    const int tid = threadIdx.x;
    const long long base = (long long)blockIdx.x * 256;
    const bool full = (base + 256 <= (long long)n_total);

    float px[9], py[9];
    float tx[4], ty[4];
    bool active = false;

    if (full) {
        // ---- coalesced global -> LDS staging ----
        // pred slab: 256*18 floats = 1152 float4 (block base is 16B-aligned:
        // 256*72*blockIdx). 4 per thread + 1 extra for half the threads.
        const float4* gp = reinterpret_cast<const float4*>(pred + base * 18);
        float4* lp = reinterpret_cast<float4*>(sp);
        #pragma unroll
        for (int j = 0; j < 4; ++j) lp[tid + 256 * j] = gp[tid + 256 * j];
        if (tid < 128) lp[tid + 1024] = gp[tid + 1024];
        // target slab: 256*8 floats = 512 float4, 2 per thread.
        const float4* gt = reinterpret_cast<const float4*>(target + base * 8);
        float4* lt = reinterpret_cast<float4*>(st);
        lt[tid]       = gt[tid];
        lt[tid + 256] = gt[tid + 256];
        __syncthreads();

        // ---- LDS -> registers (own element) ----
        const float2* mp = reinterpret_cast<const float2*>(sp) + tid * 9;
        #pragma unroll
        for (int k = 0; k < 9; ++k) { float2 v = mp[k]; px[k] = v.x; py[k] = v.y; }
        const float2* mt = reinterpret_cast<const float2*>(st) + tid * 4;
        #pragma unroll
        for (int k = 0; k < 4; ++k) { float2 v = mt[k]; tx[k] = v.x; ty[k] = v.y; }
        active = true;
    } else {
        // ---- tail block: direct (uncoalesced) loads, rare ----
        long long n = base + tid;
        if (n < n_total) {
            const float2* p = reinterpret_cast<const float2*>(pred + n * 18);
            #pragma unroll
            for (int k = 0; k < 9; ++k) { float2 v = p[k]; px[k] = v.x; py[k] = v.y; }
            const float2* t = reinterpret_cast<const float2*>(target + n * 8);
            #pragma unroll
            for (int k = 0; k < 4; ++k) { float2 v = t[k]; tx[k] = v.x; ty[k] = v.y; }
            active = true;
        }
    }

    float loss = 0.0f;
    if (active) {
        // ---- pred moments ----
        const float inv9 = 1.0f / 9.0f;
        float sx = 0.f, sy = 0.f;
        #pragma unroll
        for (int k = 0; k < 9; ++k) { sx += px[k]; sy += py[k]; }
        float mux = sx * inv9, muy = sy * inv9;
        float a = 0.f, b = 0.f, d = 0.f;   // p_var = [[a,b],[b,d]]
        #pragma unroll
        for (int k = 0; k < 9; ++k) {
            float xx = px[k] - mux, yy = py[k] - muy;
            a += xx * xx; b += xx * yy; d += yy * yy;
        }
        a = a * inv9 + 1e-6f;
        b = b * inv9;
        d = d * inv9 + 1e-6f;

        // ---- target box -> rotated Gaussian ----
        float tmux = (tx[0] + tx[1] + tx[2] + tx[3]) * 0.25f;
        float tmuy = (ty[0] + ty[1] + ty[2] + ty[3]) * 0.25f;
        float e1x = tx[1] - tx[0], e1y = ty[1] - ty[0];
        float e2x = tx[2] - tx[1], e2y = ty[2] - ty[1];
        float w = e1x * e1x + e1y * e1y;
        float h = e2x * e2x + e2y * e2y;
        float sw = sqrtf(w);
        float c = e1x / sw, s = e1y / sw;
        const float invLL = 1.0f / 36.0f;      // 1/(4*L*L), L=3
        float dw = w * invLL, dh = h * invLL;
        float tv00 = c * c * dw + s * s * dh;  // t_var = R diag(dw,dh) R^T
        float tv01 = c * s * (dw - dh);
        float tv11 = s * s * dw + c * c * dh;

        float t_det = tv00 * tv11 - tv01 * tv01;
        float p_det = a * d - b * b;
        float inv_tdet = 1.0f / t_det;

        float dx = mux - tmux, dy = muy - tmuy;
        float term1 = (dx * dx * tv11 - 2.0f * dx * dy * tv01 + dy * dy * tv00) * inv_tdet;
        float trace = (tv11 * a - 2.0f * tv01 * b + tv00 * d) * inv_tdet;
        float term2 = trace + logf(t_det / p_det);
        float kld = 0.5f * (term1 + term2) - 1.0f;
        float kl = fmaxf(kld, 1e-6f);
        loss = 1.0f - 1.0f / (2.0f + sqrtf(kl));
    }

    // ---- reduction: wave64 shuffle -> LDS -> one atomic per block ----
    #pragma unroll
    for (int off = 32; off > 0; off >>= 1)
        loss += __shfl_down(loss, off, 64);

    __shared__ float sm[4];
    int lane = tid & 63;
    int wid  = tid >> 6;
    __syncthreads();                  // reuse of LDS phases + sm
    if (lane == 0) sm[wid] = loss;
    __syncthreads();
    if (tid == 0) {
        float tot = sm[0] + sm[1] + sm[2] + sm[3];
        atomicAdd(out, tot * inv_n);
    }
}

extern "C" void kernel_launch(void* const* d_in, const int* in_sizes, int n_in,
                              void* d_out, int out_size, void* d_ws, size_t ws_size,
                              hipStream_t stream) {
    const float* pred   = (const float*)d_in[0];
    const float* target = (const float*)d_in[1];
    float* out = (float*)d_out;

    int n = in_sizes[0] / 18;   // N elements (pred is N*9*2 floats)

    hipMemsetAsync(d_out, 0, (size_t)out_size * sizeof(float), stream);

    dim3 block(256);
    dim3 grid((n + 255) / 256);
    kld_reppoints_kernel<<<grid, block, 0, stream>>>(pred, target, out, n, 1.0f / (float)n);
}

// Round 3
// 134.758 us; speedup vs baseline: 1.2235x; 1.2235x over previous
//
#include <hip/hip_runtime.h>

// KLD RepPoints loss, R2: kill the single-address atomic stream.
// R0/R1 both floored at ~60-67us with all pipes idle; WRITE_SIZE=128KB
// exposed 4096 same-line device-scope atomicAdds (32B writeback each),
// serialized at the coherence point across 8 XCDs ~= the whole 60us.
// Fix: block partials -> d_ws (plain stores), tiny second kernel reduces.
// Loads reverted to R0 direct float2 (R1 proved coalescing wasn't the issue).

__global__ __launch_bounds__(256) void kld_partial_kernel(
    const float* __restrict__ pred,    // [n][9][2]
    const float* __restrict__ target,  // [n][4][2]
    float* __restrict__ ws,            // [gridDim.x] partial sums
    int n_total)
{
    int n = blockIdx.x * blockDim.x + threadIdx.x;
    float loss = 0.0f;
    if (n < n_total) {
        // ---- pred moments ----
        const float2* p = reinterpret_cast<const float2*>(pred + (size_t)n * 18);
        float px[9], py[9];
        float sx = 0.f, sy = 0.f;
        #pragma unroll
        for (int k = 0; k < 9; ++k) {
            float2 v = p[k];
            px[k] = v.x; py[k] = v.y;
            sx += v.x; sy += v.y;
        }
        const float inv9 = 1.0f / 9.0f;
        float mux = sx * inv9, muy = sy * inv9;
        float a = 0.f, b = 0.f, d = 0.f;   // p_var = [[a,b],[b,d]]
        #pragma unroll
        for (int k = 0; k < 9; ++k) {
            float xx = px[k] - mux, yy = py[k] - muy;
            a += xx * xx; b += xx * yy; d += yy * yy;
        }
        a = a * inv9 + 1e-6f;
        b = b * inv9;
        d = d * inv9 + 1e-6f;

        // ---- target box -> rotated Gaussian ----
        const float2* t = reinterpret_cast<const float2*>(target + (size_t)n * 8);
        float2 t0 = t[0], t1 = t[1], t2 = t[2], t3 = t[3];
        float tmux = (t0.x + t1.x + t2.x + t3.x) * 0.25f;
        float tmuy = (t0.y + t1.y + t2.y + t3.y) * 0.25f;
        float e1x = t1.x - t0.x, e1y = t1.y - t0.y;
        float e2x = t2.x - t1.x, e2y = t2.y - t1.y;
        float w = e1x * e1x + e1y * e1y;
        float h = e2x * e2x + e2y * e2y;
        float sw = sqrtf(w);
        float c = e1x / sw, s = e1y / sw;
        const float invLL = 1.0f / 36.0f;      // 1/(4*L*L), L=3
        float dw = w * invLL, dh = h * invLL;
        float tv00 = c * c * dw + s * s * dh;  // t_var = R diag(dw,dh) R^T
        float tv01 = c * s * (dw - dh);
        float tv11 = s * s * dw + c * c * dh;

        float t_det = tv00 * tv11 - tv01 * tv01;
        float p_det = a * d - b * b;
        float inv_tdet = 1.0f / t_det;

        float dx = mux - tmux, dy = muy - tmuy;
        float term1 = (dx * dx * tv11 - 2.0f * dx * dy * tv01 + dy * dy * tv00) * inv_tdet;
        float trace = (tv11 * a - 2.0f * tv01 * b + tv00 * d) * inv_tdet;
        float term2 = trace + logf(t_det / p_det);
        float kld = 0.5f * (term1 + term2) - 1.0f;
        float kl = fmaxf(kld, 1e-6f);
        loss = 1.0f - 1.0f / (2.0f + sqrtf(kl));
    }

    // ---- reduction: wave64 shuffle -> LDS -> one plain store per block ----
    #pragma unroll
    for (int off = 32; off > 0; off >>= 1)
        loss += __shfl_down(loss, off, 64);

    __shared__ float sm[4];
    int lane = threadIdx.x & 63;
    int wid  = threadIdx.x >> 6;
    if (lane == 0) sm[wid] = loss;
    __syncthreads();
    if (threadIdx.x == 0)
        ws[blockIdx.x] = sm[0] + sm[1] + sm[2] + sm[3];
}

__global__ __launch_bounds__(256) void kld_final_kernel(
    const float* __restrict__ ws, float* __restrict__ out,
    int nblocks, float inv_n)
{
    float s = 0.0f;
    for (int i = threadIdx.x; i < nblocks; i += 256)
        s += ws[i];

    #pragma unroll
    for (int off = 32; off > 0; off >>= 1)
        s += __shfl_down(s, off, 64);

    __shared__ float sm[4];
    int lane = threadIdx.x & 63;
    int wid  = threadIdx.x >> 6;
    if (lane == 0) sm[wid] = s;
    __syncthreads();
    if (threadIdx.x == 0)
        out[0] = (sm[0] + sm[1] + sm[2] + sm[3]) * inv_n;
}

extern "C" void kernel_launch(void* const* d_in, const int* in_sizes, int n_in,
                              void* d_out, int out_size, void* d_ws, size_t ws_size,
                              hipStream_t stream) {
    const float* pred   = (const float*)d_in[0];
    const float* target = (const float*)d_in[1];
    float* out = (float*)d_out;
    float* ws  = (float*)d_ws;

    int n = in_sizes[0] / 18;   // N elements (pred is N*9*2 floats)
    int nblocks = (n + 255) / 256;

    kld_partial_kernel<<<nblocks, 256, 0, stream>>>(pred, target, ws, n);
    kld_final_kernel<<<1, 256, 0, stream>>>(ws, out, nblocks, 1.0f / (float)n);
}